// Round 4
// baseline (3549.948 us; speedup 1.0000x reference)
//
#include <hip/hip_runtime.h>
#include <stdint.h>

typedef unsigned short u16;
typedef unsigned long long u64;
typedef __attribute__((ext_vector_type(8))) short short8;
typedef __attribute__((ext_vector_type(4))) float f32x4;

// ---------------- device-global blob ----------------
#define SZ_BIGW    (4096ull*1024ull*2ull)          // [4096x1024] bf16, fragment-tiled
#define OFF_WHH1   (0ull)
#define OFF_WIH2   (OFF_WHH1 + SZ_BIGW)
#define OFF_WHH2   (OFF_WIH2 + SZ_BIGW)
#define OFF_WIH3   (OFF_WHH2 + SZ_BIGW)
#define OFF_WHH3   (OFF_WIH3 + SZ_BIGW)
#define OFF_MCOMB  (OFF_WHH3 + SZ_BIGW)            // W_ih1 @ W_dec  [4096x1024]
#define OFF_WIH1   (OFF_MCOMB + SZ_BIGW)           // [4096 x 160(pad of 132)]
#define SZ_WIH1    (4096ull*160ull*2ull)
#define OFF_WDECF  (OFF_WIH1 + SZ_WIH1)            // W_dec as B-op, rows f(pad160) x K=1024
#define SZ_WDECF   (160ull*1024ull*2ull)
#define OFF_WDECB  (OFF_WDECF + SZ_WDECF)          // W_dec^T as B-op, rows k(1024) x f(pad160)
#define SZ_WDECB   (1024ull*160ull*2ull)
#define OFF_XPRIM  (OFF_WDECB + SZ_WDECB)          // [64 t][20 kc][32 b][8] bf16
#define SZ_XPRIM   (64ull*5120ull*2ull)
#define OFF_H2HIST (OFF_XPRIM + SZ_XPRIM)          // 129 slots (A-layout), slot0 = prime t=63
#define SZ_HSLOT   (32768ull*2ull)                 // 64 KB per h slot
#define SZ_H2HIST  (129ull*SZ_HSLOT)
#define OFF_H0R    (OFF_H2HIST + SZ_H2HIST)        // write-once ring, depth 192
#define SZ_HR      (192ull*SZ_HSLOT)
#define OFF_H1R    (OFF_H0R + SZ_HR)
#define OFF_H2R    (OFF_H1R + SZ_HR)               // prime-phase ring, depth 64
#define SZ_H2R     (64ull*SZ_HSLOT)
#define OFF_ZEROH  (OFF_H2R + SZ_H2R)              // one zero h slot (t=0 segB input)
#define OFF_FLAGS  (OFF_ZEROH + SZ_HSLOT)          // 3 x 256 u32 flags
#define SZ_FLAGS   (4096ull)
#define OFF_BS1    (OFF_FLAGS + SZ_FLAGS)          // bias sums fp32 [4096] x4
#define OFF_BS1G   (OFF_BS1 + 16384ull)
#define OFF_BS2    (OFF_BS1G + 16384ull)
#define OFF_BS3    (OFF_BS2 + 16384ull)
#define BLOB_SIZE  (OFF_BS3 + 16384ull)

__device__ unsigned char g_blob[BLOB_SIZE];

// zero region: ZEROH + FLAGS, contiguous
#define ZERO_BYTES (SZ_HSLOT + SZ_FLAGS)

__device__ __forceinline__ u16 f2bf(float f) {
  unsigned u = __float_as_uint(f);
  u += 0x7fffu + ((u >> 16) & 1u);
  return (u16)(u >> 16);
}
__device__ __forceinline__ float sigm(float x) { return 1.f / (1.f + __expf(-x)); }
__device__ __forceinline__ float tanh_(float x) {
  x = fminf(fmaxf(x, -40.f), 40.f);
  float e = __expf(2.f * x);
  return (e - 1.f) / (e + 1.f);
}

// ---------------- prep kernels ----------------
__global__ __launch_bounds__(256) void k_zero(uint4* p, int n) {
  int i = blockIdx.x * 256 + threadIdx.x;
  for (; i < n; i += gridDim.x * 256) p[i] = make_uint4(0u, 0u, 0u, 0u);
}

// fragment-tiled layout: dst[(nt*nkc + kc)*128 + jr*8 + ke]
// perm=0: j = nt*16 + jr ; perm=1: j = (jr>>2)*1024 + nt*4 + (jr&3)  (4 h x 4 gates per tile)
__global__ __launch_bounds__(256) void k_swizzle(const float* __restrict__ src, u16* __restrict__ dst,
                                                 int J, int Jsrc, int Kpad, int Ksrc, int srcld,
                                                 int transposed, int perm) {
  int total = J * Kpad;
  int nkc = Kpad >> 3;
  for (int o = blockIdx.x * 256 + threadIdx.x; o < total; o += gridDim.x * 256) {
    int chunk = o >> 7, within = o & 127;
    int nt = chunk / nkc, kc = chunk - nt * nkc;
    int jr = within >> 3, ke = within & 7;
    int j = perm ? ((jr >> 2) * 1024 + nt * 4 + (jr & 3)) : (nt * 16 + jr);
    int k = kc * 8 + ke;
    float v = 0.f;
    if (j < Jsrc && k < Ksrc)
      v = transposed ? src[(size_t)k * srcld + j] : src[(size_t)j * srcld + k];
    dst[o] = f2bf(v);
  }
}

__global__ __launch_bounds__(256) void k_xprim(const float* __restrict__ iseq, u16* __restrict__ dst) {
  int o = blockIdx.x * 256 + threadIdx.x;
  if (o >= 64 * 5120) return;
  int t = o / 5120, rem = o - t * 5120;
  int kc = rem >> 8, b = (rem >> 3) & 31, ke = rem & 7;
  int k = kc * 8 + ke;
  float v = (k < 132) ? iseq[(size_t)b * (64 * 132) + t * 132 + k] : 0.f;
  dst[o] = f2bf(v);
}

__global__ __launch_bounds__(256) void k_bias(const float* bih1, const float* bhh1,
                                              const float* bih2, const float* bhh2,
                                              const float* bih3, const float* bhh3,
                                              const float* __restrict__ Wih1, const float* __restrict__ bdec,
                                              float* bs1, float* bs1g, float* bs2, float* bs3) {
  int j = blockIdx.x * 256 + threadIdx.x;
  if (j >= 4096) return;
  float s1 = bih1[j] + bhh1[j];
  float bc = 0.f;
  const float* wr = Wih1 + (size_t)j * 132;
  for (int f = 0; f < 132; ++f) bc += wr[f] * bdec[f];
  bs1[j] = s1;
  bs1g[j] = s1 + bc;
  bs2[j] = bih2[j] + bhh2[j];
  bs3[j] = bih3[j] + bhh3[j];
}

// Mcomb[j][k] = sum_f Wih1[j][f]*Wdec[f][k]; A-rows and C-rows permute identically.
__global__ __launch_bounds__(256) void k_mcomb(const u16* __restrict__ A, const u16* __restrict__ Bm,
                                               u16* __restrict__ dst) {
  int blk = blockIdx.x;                   // 4096 = 256 mt x 16 jg
  int mt = blk & 255, jg = blk >> 8;
  int w = threadIdx.x >> 6, l = threadIdx.x & 63, q = l >> 4, r = l & 15;
  int nt = jg * 4 + w;
  f32x4 acc = {};
  for (int ks = 0; ks < 5; ++ks) {
    short8 a = *(const short8*)(A + ((size_t)mt * 20 + ks * 4 + q) * 128 + r * 8);
    short8 b = *(const short8*)(Bm + ((size_t)nt * 20 + ks * 4 + q) * 128 + r * 8);
    acc = __builtin_amdgcn_mfma_f32_16x16x32_bf16(a, b, acc, 0, 0, 0);
  }
  int kout = nt * 16 + r;
#pragma unroll
  for (int i = 0; i < 4; ++i) {
    int jrow = q * 4 + i;
    dst[(((size_t)mt * 128 + (kout >> 3)) << 7) + jrow * 8 + (kout & 7)] = f2bf(acc[i]);
  }
}

// ---------------- persistent RNN kernel ----------------
// 256 blocks x 512 threads. Block nt owns N-tile nt: 4 h-indices x 4 gates.
// Fence-free sync (round-3 protocol, verified): write-once h rings + agent-scope
// relaxed data stores + per-block flags; visibility via producer program order
// (vmcnt(0) before flag) and LLC completion order. No threadfence.
// Round-4 change: compile-time unrolled K-loops (MLP ~16 loads in flight) and
// segA weight prefetch issued BEFORE the spin-wait (drains during the spin).

__device__ __forceinline__ void wait_all(unsigned* F, unsigned tgt) {
  if (threadIdx.x < 256) {
    while (__hip_atomic_load(F + threadIdx.x, __ATOMIC_RELAXED, __HIP_MEMORY_SCOPE_AGENT) < tgt)
      __builtin_amdgcn_s_sleep(1);
  }
  __syncthreads();
}

template<int NSB, int NSA>
__device__ __forceinline__ void layer_step(
    const u16* __restrict__ xa, const u16* __restrict__ wa_base,
    const u16* __restrict__ xb, const u16* __restrict__ wb_base,
    unsigned* waitF, unsigned wtgt,
    const float* __restrict__ bsum, float& creg, u16* __restrict__ hout,
    unsigned* arrF, unsigned aval,
    float (*red)[2][256], u64* hstage, int nt)
{
  int tid = threadIdx.x;
  int w = tid >> 6, l = tid & 63, q = l >> 4, r = l & 15;
  constexpr int NB = (NSB + 7) / 8;
  constexpr int NA = (NSA + 7) / 8;
  f32x4 acc0 = {}, acc1 = {};

  // ---- issue ALL segB loads (A + W) back-to-back for MLP ----
  short8 aB0[NB], aB1[NB], bB[NB];
#pragma unroll
  for (int i = 0; i < NB; ++i) {
    int ks = w + 8 * i;
    if ((NSB & 7) == 0 || ks < NSB) {
      const u16* xp = xb + ks * 1024 + q * 256 + r * 8;
      aB0[i] = *(const short8*)(xp);
      aB1[i] = *(const short8*)(xp + 128);
      bB[i]  = *(const short8*)(wb_base + ((size_t)(ks * 4) << 7) + l * 8);
    }
  }
  // ---- prefetch segA WEIGHTS (flag-independent) before the wait ----
  short8 bA[NA];
#pragma unroll
  for (int i = 0; i < NA; ++i) {
    int ks = w + 8 * i;
    if ((NSA & 7) == 0 || ks < NSA)
      bA[i] = *(const short8*)(wa_base + ((size_t)(ks * 4) << 7) + l * 8);
  }
  __builtin_amdgcn_sched_barrier(0);   // pin prefetch above the spin-wait

  // ---- segB MFMAs (loads above still in flight; fine-grained vmcnt) ----
#pragma unroll
  for (int i = 0; i < NB; ++i) {
    int ks = w + 8 * i;
    if ((NSB & 7) == 0 || ks < NSB) {
      acc0 = __builtin_amdgcn_mfma_f32_16x16x32_bf16(aB0[i], bB[i], acc0, 0, 0, 0);
      acc1 = __builtin_amdgcn_mfma_f32_16x16x32_bf16(aB1[i], bB[i], acc1, 0, 0, 0);
    }
  }

  if (waitF) wait_all(waitF, wtgt);

  // ---- segA A-loads (post-flag: single latency, all issued in parallel) ----
  short8 aA0[NA], aA1[NA];
#pragma unroll
  for (int i = 0; i < NA; ++i) {
    int ks = w + 8 * i;
    if ((NSA & 7) == 0 || ks < NSA) {
      const u16* xp = xa + ks * 1024 + q * 256 + r * 8;
      aA0[i] = *(const short8*)(xp);
      aA1[i] = *(const short8*)(xp + 128);
    }
  }
#pragma unroll
  for (int i = 0; i < NA; ++i) {
    int ks = w + 8 * i;
    if ((NSA & 7) == 0 || ks < NSA) {
      acc0 = __builtin_amdgcn_mfma_f32_16x16x32_bf16(aA0[i], bA[i], acc0, 0, 0, 0);
      acc1 = __builtin_amdgcn_mfma_f32_16x16x32_bf16(aA1[i], bA[i], acc1, 0, 0, 0);
    }
  }

  // ---- epilogue: cross-wave reduce, gates, cell update, h publish ----
#pragma unroll
  for (int i = 0; i < 4; ++i) { red[w][0][l * 4 + i] = acc0[i]; red[w][1][l * 4 + i] = acc1[i]; }
  __syncthreads();

  if (tid < 128) {
    int b = tid >> 2, hl = tid & 3;
    int mt = b >> 4, row = b & 15;
    int j0 = nt * 4 + hl;
    float g4[4];
#pragma unroll
    for (int g = 0; g < 4; ++g) {
      int col = g * 4 + hl;
      int lidx = ((row >> 2) * 16 + col) * 4 + (row & 3);
      float s = bsum[g * 1024 + j0];
#pragma unroll
      for (int ww = 0; ww < 8; ++ww) s += red[ww][mt][lidx];
      g4[g] = s;
    }
    float iv = sigm(g4[0]), fv = sigm(g4[1]), gv = tanh_(g4[2]), ov = sigm(g4[3]);
    float cn = fv * creg + iv * gv;
    creg = cn;
    ((u16*)hstage)[tid] = f2bf(ov * tanh_(cn));   // [b][hl]
  }
  __syncthreads();

  // wave 0: 32 u64 agent-scope stores, then flag release (after vmcnt drain)
  if (tid < 64) {
    if (tid < 32) {
      u64 v = hstage[tid];
      u64* dp = (u64*)(hout + ((size_t)(nt >> 1) * 256 + tid * 8 + (nt & 1) * 4));
      __hip_atomic_store(dp, v, __ATOMIC_RELAXED, __HIP_MEMORY_SCOPE_AGENT);
    }
    asm volatile("s_waitcnt vmcnt(0)" ::: "memory");
    if (tid == 0)
      __hip_atomic_store(arrF + nt, aval, __ATOMIC_RELAXED, __HIP_MEMORY_SCOPE_AGENT);
  }
}

__global__ __launch_bounds__(512) void k_rnn(unsigned char* blob) {
  __shared__ float red[8][2][256];
  __shared__ u64 hstage[32];
  const u16* XPRIM = (const u16*)(blob + OFF_XPRIM);
  const float* BS1 = (const float*)(blob + OFF_BS1);
  const float* BS1G = (const float*)(blob + OFF_BS1G);
  const float* BS2 = (const float*)(blob + OFF_BS2);
  const float* BS3 = (const float*)(blob + OFF_BS3);
  u16* H0R = (u16*)(blob + OFF_H0R);
  u16* H1R = (u16*)(blob + OFF_H1R);
  u16* H2R = (u16*)(blob + OFF_H2R);
  u16* H2HIST = (u16*)(blob + OFF_H2HIST);
  const u16* ZEROH = (const u16*)(blob + OFF_ZEROH);
  unsigned* FLAGS = (unsigned*)(blob + OFF_FLAGS);
  unsigned *F1 = FLAGS, *F2 = FLAGS + 256, *F3 = FLAGS + 512;

  int nt = blockIdx.x;
  // per-block weight tile bases (constant over t)
  const u16* wWIH1 = (const u16*)(blob + OFF_WIH1) + (size_t)nt * 20 * 128;
  const u16* wMCOMB = (const u16*)(blob + OFF_MCOMB) + (size_t)nt * 128 * 128;
  const u16* wWHH1 = (const u16*)(blob + OFF_WHH1) + (size_t)nt * 128 * 128;
  const u16* wWIH2 = (const u16*)(blob + OFF_WIH2) + (size_t)nt * 128 * 128;
  const u16* wWHH2 = (const u16*)(blob + OFF_WHH2) + (size_t)nt * 128 * 128;
  const u16* wWIH3 = (const u16*)(blob + OFF_WIH3) + (size_t)nt * 128 * 128;
  const u16* wWHH3 = (const u16*)(blob + OFF_WHH3) + (size_t)nt * 128 * 128;

  float c0r = 0.f, c1r = 0.f, c2r = 0.f;

  // ---- priming phase ----
  for (int t = 0; t < 64; ++t) {
    const u16* h0prev = (t == 0) ? ZEROH : H0R + (size_t)(t - 1) * 32768;
    layer_step<32, 5>(XPRIM + t * 5120, wWIH1, h0prev, wWHH1,
                      nullptr, 0u,
                      BS1, c0r, H0R + (size_t)t * 32768,
                      F1, (unsigned)(t + 1), red, hstage, nt);
    const u16* h1prev = (t == 0) ? ZEROH : H1R + (size_t)(t - 1) * 32768;
    layer_step<32, 32>(H0R + (size_t)t * 32768, wWIH2, h1prev, wWHH2,
                       F1, (unsigned)(t + 1),
                       BS2, c1r, H1R + (size_t)t * 32768,
                       F2, (unsigned)(t + 1), red, hstage, nt);
    const u16* h2prev = (t == 0) ? ZEROH : H2R + (size_t)(t - 1) * 32768;
    u16* h2out = (t < 63) ? H2R + (size_t)t * 32768 : H2HIST;
    layer_step<32, 32>(H1R + (size_t)t * 32768, wWIH3, h2prev, wWHH3,
                       F2, (unsigned)(t + 1),
                       BS3, c2r, h2out,
                       F3, (unsigned)(t + 1), red, hstage, nt);
  }
  // ---- generation phase ----
  for (int t = 64; t < 192; ++t) {
    layer_step<32, 32>(H2HIST + (size_t)(t - 64) * 32768, wMCOMB,
                       H0R + (size_t)(t - 1) * 32768, wWHH1,
                       F3, (unsigned)t,
                       BS1G, c0r, H0R + (size_t)t * 32768,
                       F1, (unsigned)(t + 1), red, hstage, nt);
    layer_step<32, 32>(H0R + (size_t)t * 32768, wWIH2,
                       H1R + (size_t)(t - 1) * 32768, wWHH2,
                       F1, (unsigned)(t + 1),
                       BS2, c1r, H1R + (size_t)t * 32768,
                       F2, (unsigned)(t + 1), red, hstage, nt);
    layer_step<32, 32>(H1R + (size_t)t * 32768, wWIH3,
                       H2HIST + (size_t)(t - 64) * 32768, wWHH3,
                       F2, (unsigned)(t + 1),
                       BS3, c2r, H2HIST + (size_t)(t - 63) * 32768,
                       F3, (unsigned)(t + 1), red, hstage, nt);
  }
}

// ---------------- batched decoder over all 128 generated h2 states ----------------
__global__ __launch_bounds__(256) void k_dec(const u16* __restrict__ h2hist, const u16* __restrict__ Wd,
                                             const float* __restrict__ bdec, float* __restrict__ out) {
  int blk = blockIdx.x;
  int s = blk / 10, nt = blk - s * 10;
  const u16* x = h2hist + (size_t)(s + 1) * 32768;
  int w = threadIdx.x >> 6, l = threadIdx.x & 63, q = l >> 4, r = l & 15;
  f32x4 acc[2] = {};
#pragma unroll
  for (int i = 0; i < 8; ++i) {
    int ks = w + 4 * i;
    const u16* xp = x + ks * 1024 + q * 256 + r * 8;
    short8 a0 = *(const short8*)(xp);
    short8 a1 = *(const short8*)(xp + 128);
    short8 bf = *(const short8*)(Wd + (((size_t)nt * 128 + ks * 4) << 7) + l * 8);
    acc[0] = __builtin_amdgcn_mfma_f32_16x16x32_bf16(a0, bf, acc[0], 0, 0, 0);
    acc[1] = __builtin_amdgcn_mfma_f32_16x16x32_bf16(a1, bf, acc[1], 0, 0, 0);
  }
  __shared__ float red[4][2][256];
#pragma unroll
  for (int mt = 0; mt < 2; ++mt)
#pragma unroll
    for (int i = 0; i < 4; ++i) red[w][mt][l * 4 + i] = acc[mt][i];
  __syncthreads();
  for (int pp = threadIdx.x; pp < 512; pp += 256) {
    int b = pp >> 4, fs = pp & 15;
    int mt = b >> 4, row = b & 15;
    int lidx = ((row >> 2) * 16 + fs) * 4 + (row & 3);
    int f = nt * 16 + fs;
    if (f < 132) {
      float v = red[0][mt][lidx] + red[1][mt][lidx] + red[2][mt][lidx] + red[3][mt][lidx] + bdec[f];
      out[(size_t)b * (128 * 132) + s * 132 + f] = v;
    }
  }
}

// ---------------- host ----------------
extern "C" void kernel_launch(void* const* d_in, const int* in_sizes, int n_in,
                              void* d_out, int out_size, void* d_ws, size_t ws_size,
                              hipStream_t stream) {
  unsigned char* blob = nullptr;
  hipGetSymbolAddress((void**)&blob, HIP_SYMBOL(g_blob));

  const float* iseq = (const float*)d_in[0];
  const float* Wih1 = (const float*)d_in[2];
  const float* Whh1 = (const float*)d_in[3];
  const float* bih1 = (const float*)d_in[4];
  const float* bhh1 = (const float*)d_in[5];
  const float* Wih2 = (const float*)d_in[6];
  const float* Whh2 = (const float*)d_in[7];
  const float* bih2 = (const float*)d_in[8];
  const float* bhh2 = (const float*)d_in[9];
  const float* Wih3 = (const float*)d_in[10];
  const float* Whh3 = (const float*)d_in[11];
  const float* bih3 = (const float*)d_in[12];
  const float* bhh3 = (const float*)d_in[13];
  const float* Wdec = (const float*)d_in[14];
  const float* bdec = (const float*)d_in[15];

  u16* tWHH1 = (u16*)(blob + OFF_WHH1);
  u16* tWIH2 = (u16*)(blob + OFF_WIH2);
  u16* tWHH2 = (u16*)(blob + OFF_WHH2);
  u16* tWIH3 = (u16*)(blob + OFF_WIH3);
  u16* tWHH3 = (u16*)(blob + OFF_WHH3);
  u16* tMCOMB = (u16*)(blob + OFF_MCOMB);
  u16* tWIH1 = (u16*)(blob + OFF_WIH1);
  u16* tWDECF = (u16*)(blob + OFF_WDECF);
  u16* tWDECB = (u16*)(blob + OFF_WDECB);
  u16* XPRIM = (u16*)(blob + OFF_XPRIM);
  u16* H2HIST = (u16*)(blob + OFF_H2HIST);
  float* BS1 = (float*)(blob + OFF_BS1);
  float* BS1G = (float*)(blob + OFF_BS1G);
  float* BS2 = (float*)(blob + OFF_BS2);
  float* BS3 = (float*)(blob + OFF_BS3);

  // prep
  k_zero<<<68, 256, 0, stream>>>((uint4*)(blob + OFF_ZEROH), (int)(ZERO_BYTES / 16));
  k_swizzle<<<2048, 256, 0, stream>>>(Whh1, tWHH1, 4096, 4096, 1024, 1024, 1024, 0, 1);
  k_swizzle<<<2048, 256, 0, stream>>>(Wih2, tWIH2, 4096, 4096, 1024, 1024, 1024, 0, 1);
  k_swizzle<<<2048, 256, 0, stream>>>(Whh2, tWHH2, 4096, 4096, 1024, 1024, 1024, 0, 1);
  k_swizzle<<<2048, 256, 0, stream>>>(Wih3, tWIH3, 4096, 4096, 1024, 1024, 1024, 0, 1);
  k_swizzle<<<2048, 256, 0, stream>>>(Whh3, tWHH3, 4096, 4096, 1024, 1024, 1024, 0, 1);
  k_swizzle<<<2048, 256, 0, stream>>>(Wih1, tWIH1, 4096, 4096, 160, 132, 132, 0, 1);
  k_swizzle<<<512, 256, 0, stream>>>(Wdec, tWDECF, 160, 132, 1024, 1024, 1024, 0, 0);
  k_swizzle<<<512, 256, 0, stream>>>(Wdec, tWDECB, 1024, 1024, 160, 132, 1024, 1, 0);
  k_xprim<<<1280, 256, 0, stream>>>(iseq, XPRIM);
  k_bias<<<16, 256, 0, stream>>>(bih1, bhh1, bih2, bhh2, bih3, bhh3, Wih1, bdec, BS1, BS1G, BS2, BS3);
  k_mcomb<<<4096, 256, 0, stream>>>(tWIH1, tWDECB, tMCOMB);

  // persistent RNN
  {
    void* args[] = { (void*)&blob };
    hipError_t ce = hipLaunchCooperativeKernel((void*)k_rnn, dim3(256), dim3(512), args, 0, stream);
    if (ce != hipSuccess) {
      k_rnn<<<dim3(256), dim3(512), 0, stream>>>(blob);
    }
  }

  // batched decoder -> d_out fp32 [32][128][132]
  k_dec<<<1280, 256, 0, stream>>>(H2HIST, tWDECF, bdec, (float*)d_out);
}

// Round 5
// 2760.075 us; speedup vs baseline: 1.2862x; 1.2862x over previous
//
#include <hip/hip_runtime.h>
#include <stdint.h>

typedef unsigned short u16;
typedef unsigned long long u64;
typedef __attribute__((ext_vector_type(8))) short short8;
typedef __attribute__((ext_vector_type(4))) float f32x4;

// ---------------- device-global blob ----------------
#define SZ_BIGW    (4096ull*1024ull*2ull)          // [4096x1024] bf16, fragment-tiled
#define OFF_WHH1   (0ull)
#define OFF_WIH2   (OFF_WHH1 + SZ_BIGW)
#define OFF_WHH2   (OFF_WIH2 + SZ_BIGW)
#define OFF_WIH3   (OFF_WHH2 + SZ_BIGW)
#define OFF_WHH3   (OFF_WIH3 + SZ_BIGW)
#define OFF_MCOMB  (OFF_WHH3 + SZ_BIGW)            // W_ih1 @ W_dec  [4096x1024]
#define OFF_WIH1   (OFF_MCOMB + SZ_BIGW)           // [4096 x 160(pad of 132)]
#define SZ_WIH1    (4096ull*160ull*2ull)
#define OFF_WDECF  (OFF_WIH1 + SZ_WIH1)            // W_dec as B-op, rows f(pad160) x K=1024
#define SZ_WDECF   (160ull*1024ull*2ull)
#define OFF_WDECB  (OFF_WDECF + SZ_WDECF)          // W_dec^T as B-op, rows k(1024) x f(pad160)
#define SZ_WDECB   (1024ull*160ull*2ull)
#define OFF_XPRIM  (OFF_WDECB + SZ_WDECB)          // [64 t][20 kc][32 b][8] bf16
#define SZ_XPRIM   (64ull*5120ull*2ull)
#define OFF_H2HIST (OFF_XPRIM + SZ_XPRIM)          // 129 slots (A-layout), slot0 = prime t=63
#define SZ_HSLOT   (32768ull*2ull)                 // 64 KB per h slot
#define SZ_H2HIST  (129ull*SZ_HSLOT)
#define OFF_H0R    (OFF_H2HIST + SZ_H2HIST)        // write-once ring, depth 192
#define SZ_HR      (192ull*SZ_HSLOT)
#define OFF_H1R    (OFF_H0R + SZ_HR)
#define OFF_H2R    (OFF_H1R + SZ_HR)               // prime-phase ring, depth 64
#define SZ_H2R     (64ull*SZ_HSLOT)
#define OFF_ZEROH  (OFF_H2R + SZ_H2R)              // one zero h slot (t=0 segB input)
#define OFF_FLAGS  (OFF_ZEROH + SZ_HSLOT)          // 3 x 256 u32 flags
#define SZ_FLAGS   (4096ull)
#define OFF_BS1    (OFF_FLAGS + SZ_FLAGS)          // bias sums fp32 [4096] x4
#define OFF_BS1G   (OFF_BS1 + 16384ull)
#define OFF_BS2    (OFF_BS1G + 16384ull)
#define OFF_BS3    (OFF_BS2 + 16384ull)
#define BLOB_SIZE  (OFF_BS3 + 16384ull)

__device__ unsigned char g_blob[BLOB_SIZE];

// zero region: ZEROH + FLAGS, contiguous
#define ZERO_BYTES (SZ_HSLOT + SZ_FLAGS)

__device__ __forceinline__ u16 f2bf(float f) {
  unsigned u = __float_as_uint(f);
  u += 0x7fffu + ((u >> 16) & 1u);
  return (u16)(u >> 16);
}
__device__ __forceinline__ float sigm(float x) { return 1.f / (1.f + __expf(-x)); }
__device__ __forceinline__ float tanh_(float x) {
  x = fminf(fmaxf(x, -40.f), 40.f);
  float e = __expf(2.f * x);
  return (e - 1.f) / (e + 1.f);
}

// ---------------- prep kernels ----------------
__global__ __launch_bounds__(256) void k_zero(uint4* p, int n) {
  int i = blockIdx.x * 256 + threadIdx.x;
  for (; i < n; i += gridDim.x * 256) p[i] = make_uint4(0u, 0u, 0u, 0u);
}

// fragment-tiled layout: dst[(nt*nkc + kc)*128 + jr*8 + ke]
// perm=0: j = nt*16 + jr ; perm=1: j = (jr>>2)*1024 + nt*4 + (jr&3)  (4 h x 4 gates per tile)
__global__ __launch_bounds__(256) void k_swizzle(const float* __restrict__ src, u16* __restrict__ dst,
                                                 int J, int Jsrc, int Kpad, int Ksrc, int srcld,
                                                 int transposed, int perm) {
  int total = J * Kpad;
  int nkc = Kpad >> 3;
  for (int o = blockIdx.x * 256 + threadIdx.x; o < total; o += gridDim.x * 256) {
    int chunk = o >> 7, within = o & 127;
    int nt = chunk / nkc, kc = chunk - nt * nkc;
    int jr = within >> 3, ke = within & 7;
    int j = perm ? ((jr >> 2) * 1024 + nt * 4 + (jr & 3)) : (nt * 16 + jr);
    int k = kc * 8 + ke;
    float v = 0.f;
    if (j < Jsrc && k < Ksrc)
      v = transposed ? src[(size_t)k * srcld + j] : src[(size_t)j * srcld + k];
    dst[o] = f2bf(v);
  }
}

__global__ __launch_bounds__(256) void k_xprim(const float* __restrict__ iseq, u16* __restrict__ dst) {
  int o = blockIdx.x * 256 + threadIdx.x;
  if (o >= 64 * 5120) return;
  int t = o / 5120, rem = o - t * 5120;
  int kc = rem >> 8, b = (rem >> 3) & 31, ke = rem & 7;
  int k = kc * 8 + ke;
  float v = (k < 132) ? iseq[(size_t)b * (64 * 132) + t * 132 + k] : 0.f;
  dst[o] = f2bf(v);
}

__global__ __launch_bounds__(256) void k_bias(const float* bih1, const float* bhh1,
                                              const float* bih2, const float* bhh2,
                                              const float* bih3, const float* bhh3,
                                              const float* __restrict__ Wih1, const float* __restrict__ bdec,
                                              float* bs1, float* bs1g, float* bs2, float* bs3) {
  int j = blockIdx.x * 256 + threadIdx.x;
  if (j >= 4096) return;
  float s1 = bih1[j] + bhh1[j];
  float bc = 0.f;
  const float* wr = Wih1 + (size_t)j * 132;
  for (int f = 0; f < 132; ++f) bc += wr[f] * bdec[f];
  bs1[j] = s1;
  bs1g[j] = s1 + bc;
  bs2[j] = bih2[j] + bhh2[j];
  bs3[j] = bih3[j] + bhh3[j];
}

// Mcomb[j][k] = sum_f Wih1[j][f]*Wdec[f][k]; A-rows and C-rows permute identically.
__global__ __launch_bounds__(256) void k_mcomb(const u16* __restrict__ A, const u16* __restrict__ Bm,
                                               u16* __restrict__ dst) {
  int blk = blockIdx.x;                   // 4096 = 256 mt x 16 jg
  int mt = blk & 255, jg = blk >> 8;
  int w = threadIdx.x >> 6, l = threadIdx.x & 63, q = l >> 4, r = l & 15;
  int nt = jg * 4 + w;
  f32x4 acc = {};
  for (int ks = 0; ks < 5; ++ks) {
    short8 a = *(const short8*)(A + ((size_t)mt * 20 + ks * 4 + q) * 128 + r * 8);
    short8 b = *(const short8*)(Bm + ((size_t)nt * 20 + ks * 4 + q) * 128 + r * 8);
    acc = __builtin_amdgcn_mfma_f32_16x16x32_bf16(a, b, acc, 0, 0, 0);
  }
  int kout = nt * 16 + r;
#pragma unroll
  for (int i = 0; i < 4; ++i) {
    int jrow = q * 4 + i;
    dst[(((size_t)mt * 128 + (kout >> 3)) << 7) + jrow * 8 + (kout & 7)] = f2bf(acc[i]);
  }
}

// ---------------- persistent RNN kernel ----------------
// 256 blocks x 512 threads. Block nt owns N-tile nt: 4 h-indices x 4 gates.
// Fence-free sync (round-3 protocol): write-once h rings + agent-scope relaxed
// data stores + per-block flags; producer orders data-before-flag via vmcnt(0).
// Round-5: __launch_bounds__(512,1) unlocks 256 VGPR/wave so the batched
// 16-load issue + cross-wait weight prefetch actually stays in registers
// (round-4's 96-VGPR cap serialized/spilled it). Prime layer-1 now also
// waits F3>=t, closing the prime-phase h2(t-1) visibility race.

__device__ __forceinline__ void wait_all(unsigned* F, unsigned tgt) {
  if (threadIdx.x < 256) {
    while (__hip_atomic_load(F + threadIdx.x, __ATOMIC_RELAXED, __HIP_MEMORY_SCOPE_AGENT) < tgt)
      __builtin_amdgcn_s_sleep(1);
  }
  __syncthreads();
}

template<int NSB, int NSA>
__device__ __forceinline__ void layer_step(
    const u16* __restrict__ xa, const u16* __restrict__ wa_base,
    const u16* __restrict__ xb, const u16* __restrict__ wb_base,
    unsigned* waitF, unsigned wtgt,
    const float* __restrict__ bsum, float& creg, u16* __restrict__ hout,
    unsigned* arrF, unsigned aval,
    float (*red)[2][256], u64* hstage, int nt)
{
  int tid = threadIdx.x;
  int w = tid >> 6, l = tid & 63, q = l >> 4, r = l & 15;
  constexpr int NB = (NSB + 7) / 8;
  constexpr int NA = (NSA + 7) / 8;
  f32x4 acc0 = {}, acc1 = {};

  // ---- issue ALL segB loads (A + W) back-to-back for MLP ----
  short8 aB0[NB], aB1[NB], bB[NB];
#pragma unroll
  for (int i = 0; i < NB; ++i) {
    int ks = w + 8 * i;
    if ((NSB & 7) == 0 || ks < NSB) {
      const u16* xp = xb + ks * 1024 + q * 256 + r * 8;
      aB0[i] = *(const short8*)(xp);
      aB1[i] = *(const short8*)(xp + 128);
      bB[i]  = *(const short8*)(wb_base + ((size_t)(ks * 4) << 7) + l * 8);
    }
  }
  // ---- prefetch segA WEIGHTS (flag-independent) before the wait ----
  short8 bA[NA];
#pragma unroll
  for (int i = 0; i < NA; ++i) {
    int ks = w + 8 * i;
    if ((NSA & 7) == 0 || ks < NSA)
      bA[i] = *(const short8*)(wa_base + ((size_t)(ks * 4) << 7) + l * 8);
  }

  // ---- segB MFMAs (loads above still in flight; fine-grained vmcnt) ----
#pragma unroll
  for (int i = 0; i < NB; ++i) {
    int ks = w + 8 * i;
    if ((NSB & 7) == 0 || ks < NSB) {
      acc0 = __builtin_amdgcn_mfma_f32_16x16x32_bf16(aB0[i], bB[i], acc0, 0, 0, 0);
      acc1 = __builtin_amdgcn_mfma_f32_16x16x32_bf16(aB1[i], bB[i], acc1, 0, 0, 0);
    }
  }
  __builtin_amdgcn_sched_barrier(0);   // keep everything above the spin-wait

  if (waitF) wait_all(waitF, wtgt);

  // ---- segA A-loads (post-flag: one parallel batch, single latency) ----
  short8 aA0[NA], aA1[NA];
#pragma unroll
  for (int i = 0; i < NA; ++i) {
    int ks = w + 8 * i;
    if ((NSA & 7) == 0 || ks < NSA) {
      const u16* xp = xa + ks * 1024 + q * 256 + r * 8;
      aA0[i] = *(const short8*)(xp);
      aA1[i] = *(const short8*)(xp + 128);
    }
  }
#pragma unroll
  for (int i = 0; i < NA; ++i) {
    int ks = w + 8 * i;
    if ((NSA & 7) == 0 || ks < NSA) {
      acc0 = __builtin_amdgcn_mfma_f32_16x16x32_bf16(aA0[i], bA[i], acc0, 0, 0, 0);
      acc1 = __builtin_amdgcn_mfma_f32_16x16x32_bf16(aA1[i], bA[i], acc1, 0, 0, 0);
    }
  }

  // ---- epilogue: cross-wave reduce, gates, cell update, h publish ----
#pragma unroll
  for (int i = 0; i < 4; ++i) { red[w][0][l * 4 + i] = acc0[i]; red[w][1][l * 4 + i] = acc1[i]; }
  __syncthreads();

  if (tid < 128) {
    int b = tid >> 2, hl = tid & 3;
    int mt = b >> 4, row = b & 15;
    int j0 = nt * 4 + hl;
    float g4[4];
#pragma unroll
    for (int g = 0; g < 4; ++g) {
      int col = g * 4 + hl;
      int lidx = ((row >> 2) * 16 + col) * 4 + (row & 3);
      float s = bsum[g * 1024 + j0];
#pragma unroll
      for (int ww = 0; ww < 8; ++ww) s += red[ww][mt][lidx];
      g4[g] = s;
    }
    float iv = sigm(g4[0]), fv = sigm(g4[1]), gv = tanh_(g4[2]), ov = sigm(g4[3]);
    float cn = fv * creg + iv * gv;
    creg = cn;
    ((u16*)hstage)[tid] = f2bf(ov * tanh_(cn));   // [b][hl]
  }
  __syncthreads();

  // wave 0: 32 u64 agent-scope stores, then flag release (after vmcnt drain)
  if (tid < 64) {
    if (tid < 32) {
      u64 v = hstage[tid];
      u64* dp = (u64*)(hout + ((size_t)(nt >> 1) * 256 + tid * 8 + (nt & 1) * 4));
      __hip_atomic_store(dp, v, __ATOMIC_RELAXED, __HIP_MEMORY_SCOPE_AGENT);
    }
    asm volatile("s_waitcnt vmcnt(0)" ::: "memory");
    if (tid == 0)
      __hip_atomic_store(arrF + nt, aval, __ATOMIC_RELAXED, __HIP_MEMORY_SCOPE_AGENT);
  }
}

__global__ __launch_bounds__(512, 1) void k_rnn(unsigned char* blob) {
  __shared__ float red[8][2][256];
  __shared__ u64 hstage[32];
  const u16* XPRIM = (const u16*)(blob + OFF_XPRIM);
  const float* BS1 = (const float*)(blob + OFF_BS1);
  const float* BS1G = (const float*)(blob + OFF_BS1G);
  const float* BS2 = (const float*)(blob + OFF_BS2);
  const float* BS3 = (const float*)(blob + OFF_BS3);
  u16* H0R = (u16*)(blob + OFF_H0R);
  u16* H1R = (u16*)(blob + OFF_H1R);
  u16* H2R = (u16*)(blob + OFF_H2R);
  u16* H2HIST = (u16*)(blob + OFF_H2HIST);
  const u16* ZEROH = (const u16*)(blob + OFF_ZEROH);
  unsigned* FLAGS = (unsigned*)(blob + OFF_FLAGS);
  unsigned *F1 = FLAGS, *F2 = FLAGS + 256, *F3 = FLAGS + 512;

  int nt = blockIdx.x;
  // per-block weight tile bases (constant over t)
  const u16* wWIH1 = (const u16*)(blob + OFF_WIH1) + (size_t)nt * 20 * 128;
  const u16* wMCOMB = (const u16*)(blob + OFF_MCOMB) + (size_t)nt * 128 * 128;
  const u16* wWHH1 = (const u16*)(blob + OFF_WHH1) + (size_t)nt * 128 * 128;
  const u16* wWIH2 = (const u16*)(blob + OFF_WIH2) + (size_t)nt * 128 * 128;
  const u16* wWHH2 = (const u16*)(blob + OFF_WHH2) + (size_t)nt * 128 * 128;
  const u16* wWIH3 = (const u16*)(blob + OFF_WIH3) + (size_t)nt * 128 * 128;
  const u16* wWHH3 = (const u16*)(blob + OFF_WHH3) + (size_t)nt * 128 * 128;

  float c0r = 0.f, c1r = 0.f, c2r = 0.f;

  // ---- priming phase ----
  for (int t = 0; t < 64; ++t) {
    const u16* h0prev = (t == 0) ? ZEROH : H0R + (size_t)(t - 1) * 32768;
    // wait F3>=t covers layer-3 segB's read of h2(t-1) via program order
    layer_step<32, 5>(XPRIM + t * 5120, wWIH1, h0prev, wWHH1,
                      F3, (unsigned)t,
                      BS1, c0r, H0R + (size_t)t * 32768,
                      F1, (unsigned)(t + 1), red, hstage, nt);
    const u16* h1prev = (t == 0) ? ZEROH : H1R + (size_t)(t - 1) * 32768;
    layer_step<32, 32>(H0R + (size_t)t * 32768, wWIH2, h1prev, wWHH2,
                       F1, (unsigned)(t + 1),
                       BS2, c1r, H1R + (size_t)t * 32768,
                       F2, (unsigned)(t + 1), red, hstage, nt);
    const u16* h2prev = (t == 0) ? ZEROH : H2R + (size_t)(t - 1) * 32768;
    u16* h2out = (t < 63) ? H2R + (size_t)t * 32768 : H2HIST;
    layer_step<32, 32>(H1R + (size_t)t * 32768, wWIH3, h2prev, wWHH3,
                       F2, (unsigned)(t + 1),
                       BS3, c2r, h2out,
                       F3, (unsigned)(t + 1), red, hstage, nt);
  }
  // ---- generation phase ----
  for (int t = 64; t < 192; ++t) {
    layer_step<32, 32>(H2HIST + (size_t)(t - 64) * 32768, wMCOMB,
                       H0R + (size_t)(t - 1) * 32768, wWHH1,
                       F3, (unsigned)t,
                       BS1G, c0r, H0R + (size_t)t * 32768,
                       F1, (unsigned)(t + 1), red, hstage, nt);
    layer_step<32, 32>(H0R + (size_t)t * 32768, wWIH2,
                       H1R + (size_t)(t - 1) * 32768, wWHH2,
                       F1, (unsigned)(t + 1),
                       BS2, c1r, H1R + (size_t)t * 32768,
                       F2, (unsigned)(t + 1), red, hstage, nt);
    layer_step<32, 32>(H1R + (size_t)t * 32768, wWIH3,
                       H2HIST + (size_t)(t - 64) * 32768, wWHH3,
                       F2, (unsigned)(t + 1),
                       BS3, c2r, H2HIST + (size_t)(t - 63) * 32768,
                       F3, (unsigned)(t + 1), red, hstage, nt);
  }
}

// ---------------- batched decoder over all 128 generated h2 states ----------------
__global__ __launch_bounds__(256) void k_dec(const u16* __restrict__ h2hist, const u16* __restrict__ Wd,
                                             const float* __restrict__ bdec, float* __restrict__ out) {
  int blk = blockIdx.x;
  int s = blk / 10, nt = blk - s * 10;
  const u16* x = h2hist + (size_t)(s + 1) * 32768;
  int w = threadIdx.x >> 6, l = threadIdx.x & 63, q = l >> 4, r = l & 15;
  f32x4 acc[2] = {};
#pragma unroll
  for (int i = 0; i < 8; ++i) {
    int ks = w + 4 * i;
    const u16* xp = x + ks * 1024 + q * 256 + r * 8;
    short8 a0 = *(const short8*)(xp);
    short8 a1 = *(const short8*)(xp + 128);
    short8 bf = *(const short8*)(Wd + (((size_t)nt * 128 + ks * 4) << 7) + l * 8);
    acc[0] = __builtin_amdgcn_mfma_f32_16x16x32_bf16(a0, bf, acc[0], 0, 0, 0);
    acc[1] = __builtin_amdgcn_mfma_f32_16x16x32_bf16(a1, bf, acc[1], 0, 0, 0);
  }
  __shared__ float red[4][2][256];
#pragma unroll
  for (int mt = 0; mt < 2; ++mt)
#pragma unroll
    for (int i = 0; i < 4; ++i) red[w][mt][l * 4 + i] = acc[mt][i];
  __syncthreads();
  for (int pp = threadIdx.x; pp < 512; pp += 256) {
    int b = pp >> 4, fs = pp & 15;
    int mt = b >> 4, row = b & 15;
    int lidx = ((row >> 2) * 16 + fs) * 4 + (row & 3);
    int f = nt * 16 + fs;
    if (f < 132) {
      float v = red[0][mt][lidx] + red[1][mt][lidx] + red[2][mt][lidx] + red[3][mt][lidx] + bdec[f];
      out[(size_t)b * (128 * 132) + s * 132 + f] = v;
    }
  }
}

// ---------------- host ----------------
extern "C" void kernel_launch(void* const* d_in, const int* in_sizes, int n_in,
                              void* d_out, int out_size, void* d_ws, size_t ws_size,
                              hipStream_t stream) {
  unsigned char* blob = nullptr;
  hipGetSymbolAddress((void**)&blob, HIP_SYMBOL(g_blob));

  const float* iseq = (const float*)d_in[0];
  const float* Wih1 = (const float*)d_in[2];
  const float* Whh1 = (const float*)d_in[3];
  const float* bih1 = (const float*)d_in[4];
  const float* bhh1 = (const float*)d_in[5];
  const float* Wih2 = (const float*)d_in[6];
  const float* Whh2 = (const float*)d_in[7];
  const float* bih2 = (const float*)d_in[8];
  const float* bhh2 = (const float*)d_in[9];
  const float* Wih3 = (const float*)d_in[10];
  const float* Whh3 = (const float*)d_in[11];
  const float* bih3 = (const float*)d_in[12];
  const float* bhh3 = (const float*)d_in[13];
  const float* Wdec = (const float*)d_in[14];
  const float* bdec = (const float*)d_in[15];

  u16* tWHH1 = (u16*)(blob + OFF_WHH1);
  u16* tWIH2 = (u16*)(blob + OFF_WIH2);
  u16* tWHH2 = (u16*)(blob + OFF_WHH2);
  u16* tWIH3 = (u16*)(blob + OFF_WIH3);
  u16* tWHH3 = (u16*)(blob + OFF_WHH3);
  u16* tMCOMB = (u16*)(blob + OFF_MCOMB);
  u16* tWIH1 = (u16*)(blob + OFF_WIH1);
  u16* tWDECF = (u16*)(blob + OFF_WDECF);
  u16* tWDECB = (u16*)(blob + OFF_WDECB);
  u16* XPRIM = (u16*)(blob + OFF_XPRIM);
  u16* H2HIST = (u16*)(blob + OFF_H2HIST);
  float* BS1 = (float*)(blob + OFF_BS1);
  float* BS1G = (float*)(blob + OFF_BS1G);
  float* BS2 = (float*)(blob + OFF_BS2);
  float* BS3 = (float*)(blob + OFF_BS3);

  // prep
  k_zero<<<68, 256, 0, stream>>>((uint4*)(blob + OFF_ZEROH), (int)(ZERO_BYTES / 16));
  k_swizzle<<<2048, 256, 0, stream>>>(Whh1, tWHH1, 4096, 4096, 1024, 1024, 1024, 0, 1);
  k_swizzle<<<2048, 256, 0, stream>>>(Wih2, tWIH2, 4096, 4096, 1024, 1024, 1024, 0, 1);
  k_swizzle<<<2048, 256, 0, stream>>>(Whh2, tWHH2, 4096, 4096, 1024, 1024, 1024, 0, 1);
  k_swizzle<<<2048, 256, 0, stream>>>(Wih3, tWIH3, 4096, 4096, 1024, 1024, 1024, 0, 1);
  k_swizzle<<<2048, 256, 0, stream>>>(Whh3, tWHH3, 4096, 4096, 1024, 1024, 1024, 0, 1);
  k_swizzle<<<2048, 256, 0, stream>>>(Wih1, tWIH1, 4096, 4096, 160, 132, 132, 0, 1);
  k_swizzle<<<512, 256, 0, stream>>>(Wdec, tWDECF, 160, 132, 1024, 1024, 1024, 0, 0);
  k_swizzle<<<512, 256, 0, stream>>>(Wdec, tWDECB, 1024, 1024, 160, 132, 1024, 1, 0);
  k_xprim<<<1280, 256, 0, stream>>>(iseq, XPRIM);
  k_bias<<<16, 256, 0, stream>>>(bih1, bhh1, bih2, bhh2, bih3, bhh3, Wih1, bdec, BS1, BS1G, BS2, BS3);
  k_mcomb<<<4096, 256, 0, stream>>>(tWIH1, tWDECB, tMCOMB);

  // persistent RNN
  {
    void* args[] = { (void*)&blob };
    hipError_t ce = hipLaunchCooperativeKernel((void*)k_rnn, dim3(256), dim3(512), args, 0, stream);
    if (ce != hipSuccess) {
      k_rnn<<<dim3(256), dim3(512), 0, stream>>>(blob);
    }
  }

  // batched decoder -> d_out fp32 [32][128][132]
  k_dec<<<1280, 256, 0, stream>>>(H2HIST, tWDECF, bdec, (float*)d_out);
}